// Round 8
// baseline (377.558 us; speedup 1.0000x reference)
//
#include <hip/hip_runtime.h>

#define B_N 32
#define S_N 1024

typedef __attribute__((ext_vector_type(8))) short sh8;
typedef __attribute__((ext_vector_type(4))) short sh4;
typedef __attribute__((ext_vector_type(4))) float f4;

__device__ __forceinline__ short f2bf(float f) {
  unsigned u = __builtin_bit_cast(unsigned, f);
  u += 0x7fff + ((u >> 16) & 1);
  return (short)(u >> 16);
}
__device__ __forceinline__ float bf2f(short s) {
  unsigned u = ((unsigned)(unsigned short)s) << 16;
  return __builtin_bit_cast(float, u);
}
__device__ __forceinline__ float dot4(f4 a, f4 w) {
  return a.x * w.x + a.y * w.y + a.z * w.z + a.w * w.w;
}

// ---------- Phase 1a: Q projection + query mask (reads queries_it ONCE) ----------
__global__ __launch_bounds__(256) void proj_q_fused(
    const float* __restrict__ in, const float* __restrict__ W,
    const float* __restrict__ bias, short* __restrict__ out,
    float* __restrict__ qm) {
  __shared__ f4 w_lds[64][33];
  __shared__ f4 a_lds[64][33];
  const int tid = threadIdx.x;
  for (int e = tid; e < 64 * 32; e += 256) w_lds[e >> 5][e & 31] = ((const f4*)W)[e];
  const f4* inb = (const f4*)(in + (size_t)blockIdx.x * 64 * 128);
  for (int e = tid; e < 64 * 32; e += 256) a_lds[e >> 5][e & 31] = inb[e];
  __syncthreads();
  if (tid < 64) {
    float s = 0.f;
#pragma unroll
    for (int d = 0; d < 32; ++d) {
      f4 a = a_lds[tid][d];
      s += fabsf(a.x) + fabsf(a.y) + fabsf(a.z) + fabsf(a.w);
    }
    qm[blockIdx.x * 64 + tid] = (s != 0.f) ? 1.f : 0.f;
  }
  const int c1 = tid & 15, r4 = tid >> 4;
  float acc[4][4];
#pragma unroll
  for (int i = 0; i < 4; ++i)
#pragma unroll
    for (int k = 0; k < 4; ++k) acc[i][k] = 0.f;
#pragma unroll
  for (int d = 0; d < 32; ++d) {
    f4 w[4], a[4];
#pragma unroll
    for (int k = 0; k < 4; ++k) w[k] = w_lds[c1 + k * 16][d];
#pragma unroll
    for (int i = 0; i < 4; ++i) a[i] = a_lds[r4 * 4 + i][d];
#pragma unroll
    for (int i = 0; i < 4; ++i)
#pragma unroll
      for (int k = 0; k < 4; ++k) acc[i][k] += dot4(a[i], w[k]);
  }
  const size_t r0 = (size_t)blockIdx.x * 64;
#pragma unroll
  for (int i = 0; i < 4; ++i)
#pragma unroll
    for (int k = 0; k < 4; ++k)
      out[(r0 + r4 * 4 + i) * 64 + c1 + k * 16] = f2bf(acc[i][k] + bias[c1 + k * 16]);
}

// ---------- Phase 1b: K projection + V (both halves, transposed) + key mask ----------
// Reads keys_it ONCE; 3 weight phases through the same LDS input tile.
__global__ __launch_bounds__(256) void proj_k_fused(
    const float* __restrict__ in,
    const float* __restrict__ Wk, const float* __restrict__ bk_,
    const float* __restrict__ Wv, const float* __restrict__ bv_,
    short* __restrict__ kit, short* __restrict__ vt, float* __restrict__ km) {
  __shared__ f4 w_lds[64][33];
  __shared__ f4 a_lds[64][33];
  __shared__ short tile[64][72];
  const int tid = threadIdx.x;
  const int c1 = tid & 15, r4 = tid >> 4;
  const f4* inb = (const f4*)(in + (size_t)blockIdx.x * 64 * 128);
  for (int e = tid; e < 64 * 32; e += 256) a_lds[e >> 5][e & 31] = inb[e];
  for (int e = tid; e < 64 * 32; e += 256) w_lds[e >> 5][e & 31] = ((const f4*)Wk)[e];
  __syncthreads();
  if (tid < 64) {
    float s = 0.f;
#pragma unroll
    for (int d = 0; d < 32; ++d) {
      f4 a = a_lds[tid][d];
      s += fabsf(a.x) + fabsf(a.y) + fabsf(a.z) + fabsf(a.w);
    }
    km[blockIdx.x * 64 + tid] = (s != 0.f) ? 1.f : 0.f;
  }
  // phase 0: kit
  {
    float acc[4][4];
#pragma unroll
    for (int i = 0; i < 4; ++i)
#pragma unroll
      for (int k = 0; k < 4; ++k) acc[i][k] = 0.f;
#pragma unroll
    for (int d = 0; d < 32; ++d) {
      f4 w[4], a[4];
#pragma unroll
      for (int k = 0; k < 4; ++k) w[k] = w_lds[c1 + k * 16][d];
#pragma unroll
      for (int i = 0; i < 4; ++i) a[i] = a_lds[r4 * 4 + i][d];
#pragma unroll
      for (int i = 0; i < 4; ++i)
#pragma unroll
        for (int k = 0; k < 4; ++k) acc[i][k] += dot4(a[i], w[k]);
    }
    const size_t r0 = (size_t)blockIdx.x * 64;
#pragma unroll
    for (int i = 0; i < 4; ++i)
#pragma unroll
      for (int k = 0; k < 4; ++k)
        kit[(r0 + r4 * 4 + i) * 64 + c1 + k * 16] = f2bf(acc[i][k] + bk_[c1 + k * 16]);
  }
  const int b = (blockIdx.x * 64) / S_N, s0 = (blockIdx.x * 64) % S_N;
  // phases 1,2: V halves (transposed store)
#pragma unroll 1
  for (int ph = 0; ph < 2; ++ph) {
    __syncthreads();  // previous w_lds / tile consumers done
    for (int e = tid; e < 64 * 32; e += 256)
      w_lds[e >> 5][e & 31] = ((const f4*)Wv)[ph * 64 * 32 + e];
    __syncthreads();
    float acc[4][4];
#pragma unroll
    for (int i = 0; i < 4; ++i)
#pragma unroll
      for (int k = 0; k < 4; ++k) acc[i][k] = 0.f;
#pragma unroll
    for (int d = 0; d < 32; ++d) {
      f4 w[4], a[4];
#pragma unroll
      for (int k = 0; k < 4; ++k) w[k] = w_lds[c1 + k * 16][d];
#pragma unroll
      for (int i = 0; i < 4; ++i) a[i] = a_lds[r4 * 4 + i][d];
#pragma unroll
      for (int i = 0; i < 4; ++i)
#pragma unroll
        for (int k = 0; k < 4; ++k) acc[i][k] += dot4(a[i], w[k]);
    }
#pragma unroll
    for (int i = 0; i < 4; ++i)
#pragma unroll
      for (int k = 0; k < 4; ++k)
        tile[c1 + k * 16][r4 * 4 + i] = f2bf(acc[i][k] + bv_[ph * 64 + c1 + k * 16]);
    __syncthreads();
    const int j = tid >> 2, seg = tid & 3;
    sh8 v0 = *(sh8*)&tile[j][seg * 16];
    sh8 v1 = *(sh8*)&tile[j][seg * 16 + 8];
    short* dst = vt + ((size_t)(b * 128 + ph * 64 + j)) * S_N + s0 + seg * 16;
    *(sh8*)dst = v0;
    *(sh8*)(dst + 8) = v1;
  }
}

// ---------- Phase 1c: ctx projections (DIN=64) ----------
__global__ __launch_bounds__(256) void proj_ctx(
    const float* __restrict__ in, const float* __restrict__ W,
    const float* __restrict__ bias, short* __restrict__ out) {
  constexpr int NS = 16;
  __shared__ f4 w_lds[64][NS + 1];
  __shared__ f4 a_lds[64][NS + 1];
  const int tid = threadIdx.x;
  for (int e = tid; e < 64 * NS; e += 256) w_lds[e / NS][e % NS] = ((const f4*)W)[e];
  const f4* inb = (const f4*)(in + (size_t)blockIdx.x * 64 * 64);
  for (int e = tid; e < 64 * NS; e += 256) a_lds[e / NS][e % NS] = inb[e];
  __syncthreads();
  const int c1 = tid & 15, r4 = tid >> 4;
  float acc[4][4];
#pragma unroll
  for (int i = 0; i < 4; ++i)
#pragma unroll
    for (int k = 0; k < 4; ++k) acc[i][k] = 0.f;
#pragma unroll
  for (int d = 0; d < NS; ++d) {
    f4 w[4], a[4];
#pragma unroll
    for (int k = 0; k < 4; ++k) w[k] = w_lds[c1 + k * 16][d];
#pragma unroll
    for (int i = 0; i < 4; ++i) a[i] = a_lds[r4 * 4 + i][d];
#pragma unroll
    for (int i = 0; i < 4; ++i)
#pragma unroll
      for (int k = 0; k < 4; ++k) acc[i][k] += dot4(a[i], w[k]);
  }
  const size_t r0 = (size_t)blockIdx.x * 64;
#pragma unroll
  for (int i = 0; i < 4; ++i)
#pragma unroll
    for (int k = 0; k < 4; ++k)
      out[(r0 + r4 * 4 + i) * 64 + c1 + k * 16] = f2bf(acc[i][k] + bias[c1 + k * 16]);
}

// ---------- Phase 2: fused dual-channel attention ----------
// Grid: 2048 blocks (XCD-swizzled), 4 waves; block = 16 q-rows, wave = 256 keys.
// Swapped QK^T: mfma(K,Q) -> C = S^T, k=grp*4+r, q=col. Per 32-key half, the
// ISSUE ORDER enforces consumption order (vmcnt is an ordered FIFO counter —
// R7's noise prefetch issued BEFORE the K loads was drained by every QK wait):
//   t0: K frags + kmask (consumed first)
//   t1: V frags into registers (consumed last this half)
//   t2: noise for NEXT half (consumed next half -> one full half of slack,
//       and never drained: all loads consumed this half were issued before it)
//   t3: QK mfma   t4: MLP+exp+P->LDS   t5: PV mfma
// Logits ~1e-3 by construction => fixed softmax max 0 is safe.
__global__ __launch_bounds__(256, 3) void attn_kernel(
    const short* __restrict__ qit, const short* __restrict__ kit,
    const short* __restrict__ qctx, const short* __restrict__ kctx,
    const short* __restrict__ vt,     // [B,128,S] bf16
    const float* __restrict__ noise,  // [B,2,S,S]
    const float* __restrict__ sigma,  // [B,2]
    const float* __restrict__ qmask, const float* __restrict__ kmask,  // [B,S]
    const float* __restrict__ qin,    // queries_it [B,S,128]
    const float* __restrict__ W1, const float* __restrict__ b1,
    const float* __restrict__ W2, const float* __restrict__ b2,
    float* __restrict__ out) {
  __shared__ __align__(16) short lds_p[4][2][16][72];  // per-wave P / bf16 O-partial
  __shared__ float lsum_lds[4][2][16];

  const int tid = threadIdx.x;
  const int wave = tid >> 6, lane = tid & 63;
  const int bid = blockIdx.x;
  const int wg = ((bid & 7) << 8) | (bid >> 3);  // XCD swizzle (2048 % 8 == 0)
  const int b = wg >> 6, qt = wg & 63;
  const int qbase = qt * 16;
  const int col = lane & 15, grp = lane >> 4;
  const int kw = wave * 256;

  const float w100 = W1[0], w101 = W1[1], w110 = W1[2], w111 = W1[3];
  const float bb10 = b1[0], bb11 = b1[1];
  const float sc = 0.125f;
  const float w200 = W2[0] * sc, w201 = W2[1] * sc, w210 = W2[2] * sc, w211 = W2[3] * sc;
  const float bb20 = b2[0] * sc, bb21 = b2[1] * sc;
  float sg0 = sigma[b * 2 + 0]; sg0 *= sg0;
  float sg1 = sigma[b * 2 + 1]; sg1 *= sg1;

  const int qrow = qbase + col;
  sh8 aqit[2], aqctx[2];
#pragma unroll
  for (int t = 0; t < 2; ++t) {
    aqit[t] = *(const sh8*)(qit + ((size_t)(b * S_N + qrow)) * 64 + grp * 8 + t * 32);
    aqctx[t] = *(const sh8*)(qctx + ((size_t)(b * S_N + qrow)) * 64 + grp * 8 + t * 32);
  }

  f4 acc[2][4];
#pragma unroll
  for (int h = 0; h < 2; ++h)
#pragma unroll
    for (int dt = 0; dt < 4; ++dt) acc[h][dt] = (f4)0.f;
  float rs0 = 0.f, rs1 = 0.f;

  const float* noise0 = noise + (size_t)(b * 2) * S_N * S_N + (size_t)qrow * S_N + grp * 4;
  const float* noise1 = noise0 + (size_t)S_N * S_N;
  const float* kmb = kmask + b * S_N + grp * 4;
  short* pw = &lds_p[wave][0][0][0];  // [2][16][72]

  // noise prefetch buffers (STATIC names -> registers, rule #20)
  f4 An0[2], An1[2], Bn0[2], Bn1[2];

  auto ldh = [&](f4(&n0)[2], f4(&n1)[2], int k0) {
    n0[0] = *(const f4*)(noise0 + k0);
    n0[1] = *(const f4*)(noise0 + k0 + 16);
    n1[0] = *(const f4*)(noise1 + k0);
    n1[1] = *(const f4*)(noise1 + k0 + 16);
  };

  auto half_step = [&](int kc, int th, const f4(&n0)[2], const f4(&n1)[2],
                       f4(&nn0)[2], f4(&nn1)[2], int knext, bool do_next) {
    const int k0 = kc + th * 32;
    // t0: K fragments + key mask (consumed first this half)
    sh8 bk[2][2], bc[2][2];
#pragma unroll
    for (int kt = 0; kt < 2; ++kt) {
      const int krow = k0 + kt * 16 + col;
#pragma unroll
      for (int t = 0; t < 2; ++t) {
        bk[kt][t] = *(const sh8*)(kit + ((size_t)(b * S_N + krow)) * 64 + grp * 8 + t * 32);
        bc[kt][t] = *(const sh8*)(kctx + ((size_t)(b * S_N + krow)) * 64 + grp * 8 + t * 32);
      }
    }
    f4 km0 = *(const f4*)(kmb + k0);
    f4 km1 = *(const f4*)(kmb + k0 + 16);
    // t1: V fragments (consumed at PV, last this half)
    sh8 bv[2][4];
#pragma unroll
    for (int h = 0; h < 2; ++h)
#pragma unroll
      for (int dt = 0; dt < 4; ++dt)
        bv[h][dt] = *(const sh8*)(vt + ((size_t)(b * 128 + h * 64 + dt * 16 + col)) * S_N +
                                  kc + grp * 8 + th * 32);
    // t2: noise for NEXT half — issued after everything consumed this half
    if (do_next) {
      nn0[0] = *(const f4*)(noise0 + knext);
      nn0[1] = *(const f4*)(noise0 + knext + 16);
      nn1[0] = *(const f4*)(noise1 + knext);
      nn1[1] = *(const f4*)(noise1 + knext + 16);
    }
    // t3: QK^T (swapped)
    f4 sit[2], sctx[2];
#pragma unroll
    for (int kt = 0; kt < 2; ++kt) {
      sit[kt] = (f4)0.f;
      sctx[kt] = (f4)0.f;
#pragma unroll
      for (int t = 0; t < 2; ++t) {
        sit[kt] = __builtin_amdgcn_mfma_f32_16x16x32_bf16(bk[kt][t], aqit[t], sit[kt], 0, 0, 0);
        sctx[kt] = __builtin_amdgcn_mfma_f32_16x16x32_bf16(bc[kt][t], aqctx[t], sctx[kt], 0, 0, 0);
      }
    }
    // t4: MLP + exp + mask; P -> LDS (PV A layout)
#pragma unroll
    for (int kt = 0; kt < 2; ++kt) {
      const f4 km = kt ? km1 : km0;
      sh4 po, pc;
#pragma unroll
      for (int r = 0; r < 4; ++r) {
        float x0 = fmaf(n0[kt][r], sg0, sit[kt][r]);
        float x1 = fmaf(n1[kt][r], sg1, sctx[kt][r]);
        float h0 = fmaxf(fmaf(w101, x1, fmaf(w100, x0, bb10)), 0.f);
        float h1 = fmaxf(fmaf(w111, x1, fmaf(w110, x0, bb11)), 0.f);
        float L0 = fmaf(w201, h1, fmaf(w200, h0, bb20));
        float L1 = fmaf(w211, h1, fmaf(w210, h0, bb21));
        float p0 = __expf(L0) * km[r];
        float p1 = __expf(L1) * km[r];
        rs0 += p0;
        rs1 += p1;
        po[r] = f2bf(p0);
        pc[r] = f2bf(p1);
      }
      *(sh4*)&pw[0 * 1152 + col * 72 + (th * 2 + kt) * 16 + grp * 4] = po;
      *(sh4*)&pw[1 * 1152 + col * 72 + (th * 2 + kt) * 16 + grp * 4] = pc;
    }
    // t5: PV (A = P from LDS; B = pre-issued V regs)
#pragma unroll
    for (int h = 0; h < 2; ++h) {
      sh8 pa = *(const sh8*)&pw[h * 1152 + col * 72 + grp * 8 + th * 32];
#pragma unroll
      for (int dt = 0; dt < 4; ++dt)
        acc[h][dt] = __builtin_amdgcn_mfma_f32_16x16x32_bf16(pa, bv[h][dt], acc[h][dt], 0, 0, 0);
    }
  };

  ldh(An0, An1, kw);  // prologue: half 0
  for (int kc = kw; kc < kw + 256; kc += 64) {
    half_step(kc, 0, An0, An1, Bn0, Bn1, kc + 32, true);
    half_step(kc, 1, Bn0, Bn1, An0, An1, kc + 64, kc + 64 < kw + 256);
  }

  // reduce sum-exp across the 4 lanes sharing q-col, stash per-wave
  rs0 += __shfl_xor(rs0, 16); rs0 += __shfl_xor(rs0, 32);
  rs1 += __shfl_xor(rs1, 16); rs1 += __shfl_xor(rs1, 32);
  if (lane < 16) {
    lsum_lds[wave][0][col] = rs0;
    lsum_lds[wave][1][col] = rs1;
  }
  // partial O -> bf16, P layout: [h][q=grp*4+r][d=dt*16+col]
#pragma unroll
  for (int h = 0; h < 2; ++h)
#pragma unroll
    for (int dt = 0; dt < 4; ++dt)
#pragma unroll
      for (int r = 0; r < 4; ++r)
        pw[h * 1152 + (grp * 4 + r) * 72 + dt * 16 + col] = f2bf(acc[h][dt][r]);
  __syncthreads();

  // epilogue: 256 threads cover 16 rows x 16 d-slots of 8
  const int orow = tid >> 4, dslot = tid & 15;
  const int hh = dslot >> 3, dd = (dslot & 7) * 8;
  const float qm = qmask[(size_t)b * S_N + qbase + orow];
  const float ls = lsum_lds[0][hh][orow] + lsum_lds[1][hh][orow] +
                   lsum_lds[2][hh][orow] + lsum_lds[3][hh][orow];
  float s[8] = {0.f, 0.f, 0.f, 0.f, 0.f, 0.f, 0.f, 0.f};
#pragma unroll
  for (int w = 0; w < 4; ++w) {
    sh8 v = *(const sh8*)&lds_p[w][hh][orow][dd];
#pragma unroll
    for (int e = 0; e < 8; ++e) s[e] += bf2f(v[e]);
  }
  const float sc2 = qm / ls;
  const size_t o = ((size_t)(b * S_N + qbase + orow)) * 128 + hh * 64 + dd;
  f4 q0 = *(const f4*)(qin + o), q1 = *(const f4*)(qin + o + 4);
  f4 r0v, r1v;
#pragma unroll
  for (int i = 0; i < 4; ++i) {
    r0v[i] = s[i] * sc2 + q0[i];
    r1v[i] = s[i + 4] * sc2 + q1[i];
  }
  *(f4*)(out + o) = r0v;
  *(f4*)(out + o + 4) = r1v;
}

extern "C" void kernel_launch(void* const* d_in, const int* in_sizes, int n_in,
                              void* d_out, int out_size, void* d_ws, size_t ws_size,
                              hipStream_t stream) {
  const float* queries_it = (const float*)d_in[0];
  const float* queries_ctx = (const float*)d_in[1];
  const float* keys_it = (const float*)d_in[2];
  const float* keys_ctx = (const float*)d_in[3];
  const float* sigma = (const float*)d_in[4];
  const float* noise = (const float*)d_in[5];
  const float* Wq_it = (const float*)d_in[6];
  const float* bq_it = (const float*)d_in[7];
  const float* Wk_it = (const float*)d_in[8];
  const float* bk_it = (const float*)d_in[9];
  const float* Wq_ctx = (const float*)d_in[10];
  const float* bq_ctx = (const float*)d_in[11];
  const float* Wk_ctx = (const float*)d_in[12];
  const float* bk_ctx = (const float*)d_in[13];
  const float* Wv = (const float*)d_in[14];
  const float* bv = (const float*)d_in[15];
  const float* W1 = (const float*)d_in[16];
  const float* b1 = (const float*)d_in[17];
  const float* W2 = (const float*)d_in[18];
  const float* b2 = (const float*)d_in[19];
  float* out = (float*)d_out;

  char* ws = (char*)d_ws;
  short* qit = (short*)(ws);                    // 4 MB
  short* kit = (short*)(ws + (4ull << 20));     // 4 MB
  short* qctx = (short*)(ws + (8ull << 20));    // 4 MB
  short* kctx = (short*)(ws + (12ull << 20));   // 4 MB
  short* vt = (short*)(ws + (16ull << 20));     // 8 MB  [B,128,S]
  float* qmask = (float*)(ws + (24ull << 20));  // 128 KB
  float* kmask = (float*)(ws + (24ull << 20) + (size_t)B_N * S_N * 4);

  const int NR = B_N * S_N;
  proj_q_fused<<<dim3(NR / 64), 256, 0, stream>>>(queries_it, Wq_it, bq_it, qit, qmask);
  proj_k_fused<<<dim3(NR / 64), 256, 0, stream>>>(keys_it, Wk_it, bk_it, Wv, bv, kit, vt, kmask);
  proj_ctx<<<dim3(NR / 64), 256, 0, stream>>>(queries_ctx, Wq_ctx, bq_ctx, qctx);
  proj_ctx<<<dim3(NR / 64), 256, 0, stream>>>(keys_ctx, Wk_ctx, bk_ctx, kctx);

  attn_kernel<<<dim3(B_N * (S_N / 16)), 256, 0, stream>>>(
      qit, kit, qctx, kctx, vt, noise, sigma, qmask, kmask, queries_it,
      W1, b1, W2, b2, out);
}

// Round 9
// 238.899 us; speedup vs baseline: 1.5804x; 1.5804x over previous
//
#include <hip/hip_runtime.h>

#define B_N 32
#define S_N 1024

typedef __attribute__((ext_vector_type(8))) short sh8;
typedef __attribute__((ext_vector_type(4))) short sh4;
typedef __attribute__((ext_vector_type(4))) float f4;

__device__ __forceinline__ short f2bf(float f) {
  unsigned u = __builtin_bit_cast(unsigned, f);
  u += 0x7fff + ((u >> 16) & 1);
  return (short)(u >> 16);
}
__device__ __forceinline__ float dot4(f4 a, f4 w) {
  return a.x * w.x + a.y * w.y + a.z * w.z + a.w * w.w;
}

// ---------- Phase 1a: Q projection + query mask (reads queries_it ONCE) ----------
__global__ __launch_bounds__(256) void proj_q_fused(
    const float* __restrict__ in, const float* __restrict__ W,
    const float* __restrict__ bias, short* __restrict__ out,
    float* __restrict__ qm) {
  __shared__ f4 w_lds[64][33];
  __shared__ f4 a_lds[64][33];
  const int tid = threadIdx.x;
  for (int e = tid; e < 64 * 32; e += 256) w_lds[e >> 5][e & 31] = ((const f4*)W)[e];
  const f4* inb = (const f4*)(in + (size_t)blockIdx.x * 64 * 128);
  for (int e = tid; e < 64 * 32; e += 256) a_lds[e >> 5][e & 31] = inb[e];
  __syncthreads();
  if (tid < 64) {
    float s = 0.f;
#pragma unroll
    for (int d = 0; d < 32; ++d) {
      f4 a = a_lds[tid][d];
      s += fabsf(a.x) + fabsf(a.y) + fabsf(a.z) + fabsf(a.w);
    }
    qm[blockIdx.x * 64 + tid] = (s != 0.f) ? 1.f : 0.f;
  }
  const int c1 = tid & 15, r4 = tid >> 4;
  float acc[4][4];
#pragma unroll
  for (int i = 0; i < 4; ++i)
#pragma unroll
    for (int k = 0; k < 4; ++k) acc[i][k] = 0.f;
#pragma unroll
  for (int d = 0; d < 32; ++d) {
    f4 w[4], a[4];
#pragma unroll
    for (int k = 0; k < 4; ++k) w[k] = w_lds[c1 + k * 16][d];
#pragma unroll
    for (int i = 0; i < 4; ++i) a[i] = a_lds[r4 * 4 + i][d];
#pragma unroll
    for (int i = 0; i < 4; ++i)
#pragma unroll
      for (int k = 0; k < 4; ++k) acc[i][k] += dot4(a[i], w[k]);
  }
  const size_t r0 = (size_t)blockIdx.x * 64;
#pragma unroll
  for (int i = 0; i < 4; ++i)
#pragma unroll
    for (int k = 0; k < 4; ++k)
      out[(r0 + r4 * 4 + i) * 64 + c1 + k * 16] = f2bf(acc[i][k] + bias[c1 + k * 16]);
}

// ---------- Phase 1b: K projection + V (both halves, transposed) + key mask ----------
__global__ __launch_bounds__(256) void proj_k_fused(
    const float* __restrict__ in,
    const float* __restrict__ Wk, const float* __restrict__ bk_,
    const float* __restrict__ Wv, const float* __restrict__ bv_,
    short* __restrict__ kit, short* __restrict__ vt, float* __restrict__ km) {
  __shared__ f4 w_lds[64][33];
  __shared__ f4 a_lds[64][33];
  __shared__ short tile[64][72];
  const int tid = threadIdx.x;
  const int c1 = tid & 15, r4 = tid >> 4;
  const f4* inb = (const f4*)(in + (size_t)blockIdx.x * 64 * 128);
  for (int e = tid; e < 64 * 32; e += 256) a_lds[e >> 5][e & 31] = inb[e];
  for (int e = tid; e < 64 * 32; e += 256) w_lds[e >> 5][e & 31] = ((const f4*)Wk)[e];
  __syncthreads();
  if (tid < 64) {
    float s = 0.f;
#pragma unroll
    for (int d = 0; d < 32; ++d) {
      f4 a = a_lds[tid][d];
      s += fabsf(a.x) + fabsf(a.y) + fabsf(a.z) + fabsf(a.w);
    }
    km[blockIdx.x * 64 + tid] = (s != 0.f) ? 1.f : 0.f;
  }
  {
    float acc[4][4];
#pragma unroll
    for (int i = 0; i < 4; ++i)
#pragma unroll
      for (int k = 0; k < 4; ++k) acc[i][k] = 0.f;
#pragma unroll
    for (int d = 0; d < 32; ++d) {
      f4 w[4], a[4];
#pragma unroll
      for (int k = 0; k < 4; ++k) w[k] = w_lds[c1 + k * 16][d];
#pragma unroll
      for (int i = 0; i < 4; ++i) a[i] = a_lds[r4 * 4 + i][d];
#pragma unroll
      for (int i = 0; i < 4; ++i)
#pragma unroll
        for (int k = 0; k < 4; ++k) acc[i][k] += dot4(a[i], w[k]);
    }
    const size_t r0 = (size_t)blockIdx.x * 64;
#pragma unroll
    for (int i = 0; i < 4; ++i)
#pragma unroll
      for (int k = 0; k < 4; ++k)
        kit[(r0 + r4 * 4 + i) * 64 + c1 + k * 16] = f2bf(acc[i][k] + bk_[c1 + k * 16]);
  }
  const int b = (blockIdx.x * 64) / S_N, s0 = (blockIdx.x * 64) % S_N;
#pragma unroll 1
  for (int ph = 0; ph < 2; ++ph) {
    __syncthreads();
    for (int e = tid; e < 64 * 32; e += 256)
      w_lds[e >> 5][e & 31] = ((const f4*)Wv)[ph * 64 * 32 + e];
    __syncthreads();
    float acc[4][4];
#pragma unroll
    for (int i = 0; i < 4; ++i)
#pragma unroll
      for (int k = 0; k < 4; ++k) acc[i][k] = 0.f;
#pragma unroll
    for (int d = 0; d < 32; ++d) {
      f4 w[4], a[4];
#pragma unroll
      for (int k = 0; k < 4; ++k) w[k] = w_lds[c1 + k * 16][d];
#pragma unroll
      for (int i = 0; i < 4; ++i) a[i] = a_lds[r4 * 4 + i][d];
#pragma unroll
      for (int i = 0; i < 4; ++i)
#pragma unroll
        for (int k = 0; k < 4; ++k) acc[i][k] += dot4(a[i], w[k]);
    }
#pragma unroll
    for (int i = 0; i < 4; ++i)
#pragma unroll
      for (int k = 0; k < 4; ++k)
        tile[c1 + k * 16][r4 * 4 + i] = f2bf(acc[i][k] + bv_[ph * 64 + c1 + k * 16]);
    __syncthreads();
    const int j = tid >> 2, seg = tid & 3;
    sh8 v0 = *(sh8*)&tile[j][seg * 16];
    sh8 v1 = *(sh8*)&tile[j][seg * 16 + 8];
    short* dst = vt + ((size_t)(b * 128 + ph * 64 + j)) * S_N + s0 + seg * 16;
    *(sh8*)dst = v0;
    *(sh8*)(dst + 8) = v1;
  }
}

// ---------- Phase 1c: ctx projections (DIN=64) ----------
__global__ __launch_bounds__(256) void proj_ctx(
    const float* __restrict__ in, const float* __restrict__ W,
    const float* __restrict__ bias, short* __restrict__ out) {
  constexpr int NS = 16;
  __shared__ f4 w_lds[64][NS + 1];
  __shared__ f4 a_lds[64][NS + 1];
  const int tid = threadIdx.x;
  for (int e = tid; e < 64 * NS; e += 256) w_lds[e / NS][e % NS] = ((const f4*)W)[e];
  const f4* inb = (const f4*)(in + (size_t)blockIdx.x * 64 * 64);
  for (int e = tid; e < 64 * NS; e += 256) a_lds[e / NS][e % NS] = inb[e];
  __syncthreads();
  const int c1 = tid & 15, r4 = tid >> 4;
  float acc[4][4];
#pragma unroll
  for (int i = 0; i < 4; ++i)
#pragma unroll
    for (int k = 0; k < 4; ++k) acc[i][k] = 0.f;
#pragma unroll
  for (int d = 0; d < NS; ++d) {
    f4 w[4], a[4];
#pragma unroll
    for (int k = 0; k < 4; ++k) w[k] = w_lds[c1 + k * 16][d];
#pragma unroll
    for (int i = 0; i < 4; ++i) a[i] = a_lds[r4 * 4 + i][d];
#pragma unroll
    for (int i = 0; i < 4; ++i)
#pragma unroll
      for (int k = 0; k < 4; ++k) acc[i][k] += dot4(a[i], w[k]);
  }
  const size_t r0 = (size_t)blockIdx.x * 64;
#pragma unroll
  for (int i = 0; i < 4; ++i)
#pragma unroll
    for (int k = 0; k < 4; ++k)
      out[(r0 + r4 * 4 + i) * 64 + c1 + k * 16] = f2bf(acc[i][k] + bias[c1 + k * 16]);
}

// ---------- Phase 2: fused attention, LDS-staged K/V (canonical tile form) ----------
// Grid: 512 blocks (XCD-swizzled), 4 waves. Block = 64 q-rows (16/wave); all
// waves share each 64-key chunk's K/kctx/V tiles, staged cooperatively into
// LDS with fully-coalesced loads (fixes the 16-line-per-instruction gathers
// of the direct-fragment design), fragments read back with XOR slot-swizzle
// (slot ^= row&7) to avoid the 128B-stride bank conflict. Noise rides in
// VGPRs, issued during the staging phase (latency hidden by the stage wait).
// P (bf16) overlays the K arena after barB. 3 barriers/chunk.
// Logits ~1e-3 by construction => fixed softmax max 0 is safe.
__global__ __launch_bounds__(256, 3) void attn_kernel(
    const short* __restrict__ qit, const short* __restrict__ kit,
    const short* __restrict__ qctx, const short* __restrict__ kctx,
    const short* __restrict__ vt,     // [B,128,S] bf16
    const float* __restrict__ noise,  // [B,2,S,S]
    const float* __restrict__ sigma,  // [B,2]
    const float* __restrict__ qmask, const float* __restrict__ kmask,  // [B,S]
    const float* __restrict__ qin,    // queries_it [B,S,128]
    const float* __restrict__ W1, const float* __restrict__ b1,
    const float* __restrict__ W2, const float* __restrict__ b2,
    float* __restrict__ out) {
  // arena rows 0-63: kit tile [64k][64d]; rows 64-127: kctx. After barB the
  // region is reused for P: wave w rows w*32 + ch*16 + q. 16B-slot XOR swizzle.
  __shared__ __align__(16) short arena[128][64];   // 16 KB
  __shared__ __align__(16) short vt_lds[128][64];  // 16 KB [d][s-chunk]
  __shared__ float lsum_lds[4][2][16];

  const int tid = threadIdx.x;
  const int wave = tid >> 6, lane = tid & 63;
  const int bid = blockIdx.x;
  const int wg = ((bid & 7) << 6) | (bid >> 3);  // XCD swizzle (512 % 8 == 0)
  const int b = wg >> 4, qt = wg & 15;
  const int qbase = qt * 64 + wave * 16;
  const int col = lane & 15, grp = lane >> 4;

  const float w100 = W1[0], w101 = W1[1], w110 = W1[2], w111 = W1[3];
  const float bb10 = b1[0], bb11 = b1[1];
  const float sc = 0.125f;
  const float w200 = W2[0] * sc, w201 = W2[1] * sc, w210 = W2[2] * sc, w211 = W2[3] * sc;
  const float bb20 = b2[0] * sc, bb21 = b2[1] * sc;
  float sg0 = sigma[b * 2 + 0]; sg0 *= sg0;
  float sg1 = sigma[b * 2 + 1]; sg1 *= sg1;

  // Q fragments (B-operand of swapped QK^T): q = col, d = grp*8 + t*32
  const int qrow = qbase + col;
  sh8 aqit[2], aqctx[2];
#pragma unroll
  for (int t = 0; t < 2; ++t) {
    aqit[t] = *(const sh8*)(qit + ((size_t)(b * S_N + qrow)) * 64 + grp * 8 + t * 32);
    aqctx[t] = *(const sh8*)(qctx + ((size_t)(b * S_N + qrow)) * 64 + grp * 8 + t * 32);
  }

  f4 acc[2][4];
#pragma unroll
  for (int h = 0; h < 2; ++h)
#pragma unroll
    for (int dt = 0; dt < 4; ++dt) acc[h][dt] = (f4)0.f;
  float rs0 = 0.f, rs1 = 0.f;

  const float* noise0 = noise + (size_t)(b * 2) * S_N * S_N + (size_t)qrow * S_N + grp * 4;
  const float* noise1 = noise0 + (size_t)S_N * S_N;
  const float* kmb = kmask + b * S_N + grp * 4;
  const short* kit_g = kit + (size_t)b * S_N * 64;
  const short* kctx_g = kctx + (size_t)b * S_N * 64;
  const short* vt_g = vt + (size_t)b * 128 * S_N;
  short* ar = &arena[0][0];
  short* vl = &vt_lds[0][0];
  // staging indices (per-thread, constant): unit u -> row u>>3, slot u&7
  const int sw_key = col & 7;  // XOR key for this lane's fragment rows

#pragma unroll 1
  for (int kc = 0; kc < S_N; kc += 64) {
    // --- staging: issue loads (coalesced), then writes (swizzled dest)
    sh8 stg[8];
#pragma unroll
    for (int s = 0; s < 2; ++s) {  // kit (8KB) + kctx: 2 units each/thread
      const int u = s * 256 + tid, row = u >> 3, sl = u & 7;
      stg[s] = *(const sh8*)(kit_g + (size_t)(kc + row) * 64 + sl * 8);
      stg[2 + s] = *(const sh8*)(kctx_g + (size_t)(kc + row) * 64 + sl * 8);
    }
#pragma unroll
    for (int s = 0; s < 4; ++s) {  // vt tile (16KB): 4 units/thread
      const int u = s * 256 + tid, d = u >> 3, sl = u & 7;
      stg[4 + s] = *(const sh8*)(vt_g + (size_t)d * S_N + kc + sl * 8);
    }
    // noise for this chunk (issued after staging loads; consumed after barB)
    f4 nb0[4], nb1[4];
#pragma unroll
    for (int kt = 0; kt < 4; ++kt) {
      nb0[kt] = *(const f4*)(noise0 + kc + kt * 16);
      nb1[kt] = *(const f4*)(noise1 + kc + kt * 16);
    }
#pragma unroll
    for (int s = 0; s < 2; ++s) {
      const int u = s * 256 + tid, row = u >> 3, sl = u & 7;
      const int swz = (sl ^ (row & 7)) * 8;
      *(sh8*)&ar[row * 64 + swz] = stg[s];
      *(sh8*)&ar[(64 + row) * 64 + swz] = stg[2 + s];
    }
#pragma unroll
    for (int s = 0; s < 4; ++s) {
      const int u = s * 256 + tid, d = u >> 3, sl = u & 7;
      *(sh8*)&vl[d * 64 + ((sl ^ (d & 7)) * 8)] = stg[4 + s];
    }
    __syncthreads();  // barA: tiles visible

    // --- QK^T (swapped): C = S^T, k = grp*4+r, q = col
    f4 sit[4], sctx[4];
#pragma unroll
    for (int kt = 0; kt < 4; ++kt) {
      const int krow = kt * 16 + col;
      sit[kt] = (f4)0.f;
      sctx[kt] = (f4)0.f;
#pragma unroll
      for (int t = 0; t < 2; ++t) {
        const int so = ((grp + 4 * t) ^ sw_key) * 8;
        sh8 bk = *(const sh8*)&ar[krow * 64 + so];
        sit[kt] = __builtin_amdgcn_mfma_f32_16x16x32_bf16(bk, aqit[t], sit[kt], 0, 0, 0);
        sh8 bc = *(const sh8*)&ar[(64 + krow) * 64 + so];
        sctx[kt] = __builtin_amdgcn_mfma_f32_16x16x32_bf16(bc, aqctx[t], sctx[kt], 0, 0, 0);
      }
    }
    __syncthreads();  // barB: all QK reads done -> arena reusable as P

    // --- MLP + exp + mask; P -> arena (swizzled, PV-A layout)
    const int prow0 = (wave << 5) + col;  // ch0; ch1 at +16
#pragma unroll
    for (int kt = 0; kt < 4; ++kt) {
      f4 km = *(const f4*)(kmb + kc + kt * 16);
      sh4 po, pc;
#pragma unroll
      for (int r = 0; r < 4; ++r) {
        float x0 = fmaf(nb0[kt][r], sg0, sit[kt][r]);
        float x1 = fmaf(nb1[kt][r], sg1, sctx[kt][r]);
        float h0 = fmaxf(fmaf(w101, x1, fmaf(w100, x0, bb10)), 0.f);
        float h1 = fmaxf(fmaf(w111, x1, fmaf(w110, x0, bb11)), 0.f);
        float L0 = fmaf(w201, h1, fmaf(w200, h0, bb20));
        float L1 = fmaf(w211, h1, fmaf(w210, h0, bb21));
        float p0 = __expf(L0) * km[r];
        float p1 = __expf(L1) * km[r];
        rs0 += p0;
        rs1 += p1;
        po[r] = f2bf(p0);
        pc[r] = f2bf(p1);
      }
      // k-shorts = kt*16 + grp*4 -> slot = kt*2 + (grp>>1), half = grp&1
      const int sl = kt * 2 + (grp >> 1);
      const int off = ((sl ^ sw_key) * 8) + (grp & 1) * 4;
      *(sh4*)&ar[prow0 * 64 + off] = po;
      *(sh4*)&ar[(prow0 + 16) * 64 + off] = pc;
    }
    // --- PV: A = P (own wave region), B = V tile
#pragma unroll
    for (int h = 0; h < 2; ++h) {
#pragma unroll
      for (int t = 0; t < 2; ++t) {
        const int so = ((grp + 4 * t) ^ sw_key) * 8;
        sh8 pa = *(const sh8*)&ar[(prow0 + h * 16) * 64 + so];
#pragma unroll
        for (int dt = 0; dt < 4; ++dt) {
          const int drow = h * 64 + dt * 16 + col;
          sh8 bv = *(const sh8*)&vl[drow * 64 + so];
          acc[h][dt] = __builtin_amdgcn_mfma_f32_16x16x32_bf16(pa, bv, acc[h][dt], 0, 0, 0);
        }
      }
    }
    __syncthreads();  // barC: PV reads done -> next chunk may overwrite
  }

  // sum-exp: reduce over the 4 lanes sharing q=col, redistribute via LDS
  rs0 += __shfl_xor(rs0, 16); rs0 += __shfl_xor(rs0, 32);
  rs1 += __shfl_xor(rs1, 16); rs1 += __shfl_xor(rs1, 32);
  if (lane < 16) {
    lsum_lds[wave][0][col] = rs0;
    lsum_lds[wave][1][col] = rs1;
  }
  __syncthreads();
  f4 ls0 = *(const f4*)&lsum_lds[wave][0][grp * 4];
  f4 ls1 = *(const f4*)&lsum_lds[wave][1][grp * 4];
  f4 qm4 = *(const f4*)(qmask + (size_t)b * S_N + qbase + grp * 4);
  // epilogue: acc element = O[q = grp*4+r][d = h*64 + dt*16 + col]
#pragma unroll
  for (int h = 0; h < 2; ++h)
#pragma unroll
    for (int dt = 0; dt < 4; ++dt)
#pragma unroll
      for (int r = 0; r < 4; ++r) {
        const float s2 = qm4[r] / (h ? ls1[r] : ls0[r]);
        const size_t o = ((size_t)(b * S_N + qbase + grp * 4 + r)) * 128 + h * 64 + dt * 16 + col;
        out[o] = acc[h][dt][r] * s2 + qin[o];
      }
}

extern "C" void kernel_launch(void* const* d_in, const int* in_sizes, int n_in,
                              void* d_out, int out_size, void* d_ws, size_t ws_size,
                              hipStream_t stream) {
  const float* queries_it = (const float*)d_in[0];
  const float* queries_ctx = (const float*)d_in[1];
  const float* keys_it = (const float*)d_in[2];
  const float* keys_ctx = (const float*)d_in[3];
  const float* sigma = (const float*)d_in[4];
  const float* noise = (const float*)d_in[5];
  const float* Wq_it = (const float*)d_in[6];
  const float* bq_it = (const float*)d_in[7];
  const float* Wk_it = (const float*)d_in[8];
  const float* bk_it = (const float*)d_in[9];
  const float* Wq_ctx = (const float*)d_in[10];
  const float* bq_ctx = (const float*)d_in[11];
  const float* Wk_ctx = (const float*)d_in[12];
  const float* bk_ctx = (const float*)d_in[13];
  const float* Wv = (const float*)d_in[14];
  const float* bv = (const float*)d_in[15];
  const float* W1 = (const float*)d_in[16];
  const float* b1 = (const float*)d_in[17];
  const float* W2 = (const float*)d_in[18];
  const float* b2 = (const float*)d_in[19];
  float* out = (float*)d_out;

  char* ws = (char*)d_ws;
  short* qit = (short*)(ws);                    // 4 MB
  short* kit = (short*)(ws + (4ull << 20));     // 4 MB
  short* qctx = (short*)(ws + (8ull << 20));    // 4 MB
  short* kctx = (short*)(ws + (12ull << 20));   // 4 MB
  short* vt = (short*)(ws + (16ull << 20));     // 8 MB  [B,128,S]
  float* qmask = (float*)(ws + (24ull << 20));  // 128 KB
  float* kmask = (float*)(ws + (24ull << 20) + (size_t)B_N * S_N * 4);

  const int NR = B_N * S_N;
  proj_q_fused<<<dim3(NR / 64), 256, 0, stream>>>(queries_it, Wq_it, bq_it, qit, qmask);
  proj_k_fused<<<dim3(NR / 64), 256, 0, stream>>>(keys_it, Wk_it, bk_it, Wv, bv, kit, vt, kmask);
  proj_ctx<<<dim3(NR / 64), 256, 0, stream>>>(queries_ctx, Wq_ctx, bq_ctx, qctx);
  proj_ctx<<<dim3(NR / 64), 256, 0, stream>>>(keys_ctx, Wk_ctx, bk_ctx, kctx);

  attn_kernel<<<dim3(B_N * (S_N / 64)), 256, 0, stream>>>(
      qit, kit, qctx, kctx, vt, noise, sigma, qmask, kmask, queries_it,
      W1, b1, W2, b2, out);
}